// Round 4
// baseline (200.742 us; speedup 1.0000x reference)
//
#include <hip/hip_runtime.h>

// Problem constants (from reference): B,T,L,R,E,F
#define B_ 8
#define T_ 16
#define L_ 128
#define R_ 1024
#define E_ 5
#define F_ 512

typedef short short8 __attribute__((ext_vector_type(8)));
typedef float floatx4 __attribute__((ext_vector_type(4)));

// fp32 -> bf16 bits, round-half-up (matches previously verified kernel)
__device__ __forceinline__ unsigned short f2bf(float f) {
  unsigned u = __float_as_uint(f);
  return (unsigned short)((u + 0x8000u) >> 16);
}

__device__ __forceinline__ short8 pack8(floatx4 lo, floatx4 hi) {
  short8 v;
  v[0] = (short)f2bf(lo[0]); v[1] = (short)f2bf(lo[1]);
  v[2] = (short)f2bf(lo[2]); v[3] = (short)f2bf(lo[3]);
  v[4] = (short)f2bf(hi[0]); v[5] = (short)f2bf(hi[1]);
  v[6] = (short)f2bf(hi[2]); v[7] = (short)f2bf(hi[3]);
  return v;
}

// 8-consecutive-float fragment (lane-local 32B): two dwordx4 loads
struct Frag { floatx4 lo, hi; };
__device__ __forceinline__ Frag ldfrag(const float* __restrict__ p) {
  Frag f;
  f.lo = *(const floatx4*)p;
  f.hi = *(const floatx4*)(p + 4);
  return f;
}

// ---------------------------------------------------------------------------
// Kernel 1: rot = QR(pre_rot).Q (LAPACK Householder convention), then
// new_lig[b,t,l,:] = rot[b,t] @ lig_coord[b,l] + trans[b,t].
// Also zeroes out[bt] so the fused kernel can atomicAdd.
// ---------------------------------------------------------------------------
__global__ void prep_kernel(const float* __restrict__ lig_coord,
                            const float* __restrict__ pre_rot,
                            const float* __restrict__ trans,
                            float* __restrict__ new_lig,
                            float* __restrict__ out) {
  int bt = blockIdx.x;
  __shared__ float Qs[3][3];
  if (threadIdx.x == 0) {
    out[bt] = 0.f;                      // zero output for atomic accumulation
    float a[3][3], q[3][3];
    #pragma unroll
    for (int i = 0; i < 3; ++i)
      #pragma unroll
      for (int j = 0; j < 3; ++j) {
        a[i][j] = pre_rot[(bt * 3 + i) * 3 + j];
        q[i][j] = (i == j) ? 1.f : 0.f;
      }
    for (int k = 0; k < 3; ++k) {
      float alpha = a[k][k];
      float xn2 = 0.f;
      for (int i = k + 1; i < 3; ++i) xn2 += a[i][k] * a[i][k];
      float nrm = sqrtf(alpha * alpha + xn2);
      if (xn2 > 0.f && nrm > 0.f) {
        float beta = (alpha >= 0.f) ? -nrm : nrm;
        float tau = (beta - alpha) / beta;
        float inv = 1.f / (alpha - beta);
        float v[3] = {0.f, 0.f, 0.f};
        v[k] = 1.f;
        for (int i = k + 1; i < 3; ++i) v[i] = a[i][k] * inv;
        for (int j = k; j < 3; ++j) {
          float w = 0.f;
          for (int i = k; i < 3; ++i) w += v[i] * a[i][j];
          w *= tau;
          for (int i = k; i < 3; ++i) a[i][j] -= w * v[i];
        }
        for (int i = 0; i < 3; ++i) {
          float w = 0.f;
          for (int j = k; j < 3; ++j) w += q[i][j] * v[j];
          w *= tau;
          for (int j = k; j < 3; ++j) q[i][j] -= w * v[j];
        }
      }
    }
    for (int i = 0; i < 3; ++i)
      for (int j = 0; j < 3; ++j) Qs[i][j] = q[i][j];
  }
  __syncthreads();
  int b = bt >> 4;
  int l = threadIdx.x;
  float cx = lig_coord[(b * L_ + l) * 3 + 0];
  float cy = lig_coord[(b * L_ + l) * 3 + 1];
  float cz = lig_coord[(b * L_ + l) * 3 + 2];
  float nx = Qs[0][0] * cx + Qs[0][1] * cy + Qs[0][2] * cz + trans[bt * 3 + 0];
  float ny = Qs[1][0] * cx + Qs[1][1] * cy + Qs[1][2] * cz + trans[bt * 3 + 1];
  float nz = Qs[2][0] * cx + Qs[2][1] * cy + Qs[2][2] * cz + trans[bt * 3 + 2];
  float* o = new_lig + ((size_t)bt * L_ + l) * 3;
  o[0] = nx; o[1] = ny; o[2] = nz;
}

// ---------------------------------------------------------------------------
// Phase B (templated on e-index): U[t] += sum_pairs acc * d^exp[e].
// exps = [-3,-2,-1,1,2] -> specialized power ladder (0-3 ops from rsqrt).
// t-loop rolled x4 (inner 4 unrolled); wave-reduce each t into smr[wave][t].
// ---------------------------------------------------------------------------
template <int EIDX>
__device__ __forceinline__ void phaseB(const floatx4 (&acc)[2][4],
                                       const float* nlp,
                                       const float (&rcx)[4],
                                       const float (&rcy)[4],
                                       const float (&rcz)[4],
                                       int wm, int quad, int lane, int wave,
                                       float (*smr)[T_]) {
  #pragma unroll 1
  for (int tg = 0; tg < 4; ++tg) {
    #pragma unroll
    for (int it = 0; it < 4; ++it) {
      const int t = tg * 4 + it;
      float uacc = 0.f;
      #pragma unroll
      for (int i = 0; i < 2; ++i)
        #pragma unroll
        for (int reg = 0; reg < 4; ++reg) {
          const int m = wm + i * 16 + quad * 4 + reg;
          const float* np = nlp + (t * L_ + m) * 3;   // quad-uniform: broadcast
          const float nx = np[0], ny = np[1], nz = np[2];
          #pragma unroll
          for (int j = 0; j < 4; ++j) {
            float dx = nx - rcx[j];
            float dy = ny - rcy[j];
            float dz = nz - rcz[j];
            float d2 = fmaf(dx, dx, fmaf(dy, dy, dz * dz));
            d2 = fmaxf(d2, 1e-20f);
            float p;
            if constexpr (EIDX == 0) {        // d^-3
              float rs = rsqrtf(d2); p = rs * rs * rs;
            } else if constexpr (EIDX == 1) { // d^-2
              float rs = rsqrtf(d2); p = rs * rs;
            } else if constexpr (EIDX == 2) { // d^-1
              p = rsqrtf(d2);
            } else if constexpr (EIDX == 3) { // d^1
              float rs = rsqrtf(d2); p = d2 * rs;
            } else {                          // d^2
              p = d2;
            }
            uacc = fmaf(acc[i][j][reg], p, uacc);
          }
        }
      #pragma unroll
      for (int m_ = 32; m_ > 0; m_ >>= 1) uacc += __shfl_xor(uacc, m_, 64);
      if (lane == 0) smr[wave][t] = uacc;
    }
  }
}

// ---------------------------------------------------------------------------
// Kernel 2 (fused-by-e, DIRECT-LOAD GEMM): grid (16 rt, 5 e, 8 b) = 640
// blocks x 256 threads (4 waves). Wave tile 32M x 64N.
//  Phase A: barrier-free MFMA GEMM. Each lane loads its fragments straight
//           from global: A row = wm+i*16+(lane&15), k = (lane>>4)*8+[0..8) —
//           8 consecutive floats = 2 dwordx4 off a fixed base pointer
//           (4 lanes/row form one 128B segment). 12 loads/chunk/wave,
//           register double-buffered (named bufs, no runtime indexing).
//           No LDS, no s_barrier, no explicit waitcnt in phase A.
//           Redundant A/B re-reads are L1/L2/L3-absorbed (unique ~95MB).
//  Phase B: mask acc, distance/power (e-specialized), reduce, atomicAdd.
// ---------------------------------------------------------------------------
__launch_bounds__(256)
__global__ void fused_kernel(const float* __restrict__ lig_feat,
                             const float* __restrict__ rec_feat,
                             const float* __restrict__ rec_coord,
                             const int* __restrict__ lig_counts,
                             const int* __restrict__ rec_counts,
                             const float* __restrict__ new_lig,
                             float* __restrict__ out) {
  const int rt = blockIdx.x;    // 0..15
  const int e  = blockIdx.y;    // 0..4
  const int b  = blockIdx.z;    // 0..7
  const int r0 = rt * 64;
  const int recN = rec_counts[b];
  if (r0 >= recN) return;       // fully-masked tile contributes 0

  __shared__ __align__(16) float nls[T_ * L_ * 3];  // 24KB new_lig[b]
  __shared__ float smr[4][T_];

  const int tid  = threadIdx.x;
  const int wave = tid >> 6;
  const int lane = tid & 63;
  const int lrow = lane & 15;
  const int quad = lane >> 4;
  const int wm   = wave * 32;

  // stage new_lig[b] ([T,L,3] = 24KB) into LDS up front; visibility barrier
  // comes after the GEMM (phase B is the only reader).
  {
    const floatx4* src = (const floatx4*)(new_lig + (size_t)b * T_ * L_ * 3);
    floatx4* dst = (floatx4*)nls;       // 6144 floats = 1536 float4
    #pragma unroll
    for (int i = 0; i < 6; ++i) dst[tid + i * 256] = src[tid + i * 256];
  }

  // fragment base pointers: lane-local, k advances by 32 floats (128B)/chunk
  const float* pA0 = lig_feat + ((size_t)(b * L_ + wm + 0  + lrow) * E_ + e) * F_ + quad * 8;
  const float* pA1 = lig_feat + ((size_t)(b * L_ + wm + 16 + lrow) * E_ + e) * F_ + quad * 8;
  const float* pB0 = rec_feat + ((size_t)(b * R_ + r0 + 0  + lrow) * E_ + e) * F_ + quad * 8;
  const float* pB1 = rec_feat + ((size_t)(b * R_ + r0 + 16 + lrow) * E_ + e) * F_ + quad * 8;
  const float* pB2 = rec_feat + ((size_t)(b * R_ + r0 + 32 + lrow) * E_ + e) * F_ + quad * 8;
  const float* pB3 = rec_feat + ((size_t)(b * R_ + r0 + 48 + lrow) * E_ + e) * F_ + quad * 8;

  floatx4 acc[2][4];
  #pragma unroll
  for (int i = 0; i < 2; ++i)
    #pragma unroll
    for (int j = 0; j < 4; ++j)
      acc[i][j] = (floatx4){0.f, 0.f, 0.f, 0.f};

  // prologue: chunk 0 -> buffer a
  Frag A0a = ldfrag(pA0), A1a = ldfrag(pA1);
  Frag B0a = ldfrag(pB0), B1a = ldfrag(pB1), B2a = ldfrag(pB2), B3a = ldfrag(pB3);

  #pragma unroll 1
  for (int kc = 0; kc < 16; kc += 2) {
    // issue chunk kc+1 -> buffer b (12 independent dwordx4)
    const int o1 = (kc + 1) * 32;
    Frag A0b = ldfrag(pA0 + o1), A1b = ldfrag(pA1 + o1);
    Frag B0b = ldfrag(pB0 + o1), B1b = ldfrag(pB1 + o1);
    Frag B2b = ldfrag(pB2 + o1), B3b = ldfrag(pB3 + o1);

    // compute chunk kc from buffer a (waits only on buffer-a loads)
    {
      short8 af0 = pack8(A0a.lo, A0a.hi);
      short8 af1 = pack8(A1a.lo, A1a.hi);
      short8 bf0 = pack8(B0a.lo, B0a.hi);
      short8 bf1 = pack8(B1a.lo, B1a.hi);
      short8 bf2 = pack8(B2a.lo, B2a.hi);
      short8 bf3 = pack8(B3a.lo, B3a.hi);
      acc[0][0] = __builtin_amdgcn_mfma_f32_16x16x32_bf16(af0, bf0, acc[0][0], 0, 0, 0);
      acc[0][1] = __builtin_amdgcn_mfma_f32_16x16x32_bf16(af0, bf1, acc[0][1], 0, 0, 0);
      acc[0][2] = __builtin_amdgcn_mfma_f32_16x16x32_bf16(af0, bf2, acc[0][2], 0, 0, 0);
      acc[0][3] = __builtin_amdgcn_mfma_f32_16x16x32_bf16(af0, bf3, acc[0][3], 0, 0, 0);
      acc[1][0] = __builtin_amdgcn_mfma_f32_16x16x32_bf16(af1, bf0, acc[1][0], 0, 0, 0);
      acc[1][1] = __builtin_amdgcn_mfma_f32_16x16x32_bf16(af1, bf1, acc[1][1], 0, 0, 0);
      acc[1][2] = __builtin_amdgcn_mfma_f32_16x16x32_bf16(af1, bf2, acc[1][2], 0, 0, 0);
      acc[1][3] = __builtin_amdgcn_mfma_f32_16x16x32_bf16(af1, bf3, acc[1][3], 0, 0, 0);
    }

    // issue chunk kc+2 -> buffer a (skip on last iteration)
    if (kc + 2 < 16) {
      const int o2 = (kc + 2) * 32;
      A0a = ldfrag(pA0 + o2); A1a = ldfrag(pA1 + o2);
      B0a = ldfrag(pB0 + o2); B1a = ldfrag(pB1 + o2);
      B2a = ldfrag(pB2 + o2); B3a = ldfrag(pB3 + o2);
    }

    // compute chunk kc+1 from buffer b
    {
      short8 af0 = pack8(A0b.lo, A0b.hi);
      short8 af1 = pack8(A1b.lo, A1b.hi);
      short8 bf0 = pack8(B0b.lo, B0b.hi);
      short8 bf1 = pack8(B1b.lo, B1b.hi);
      short8 bf2 = pack8(B2b.lo, B2b.hi);
      short8 bf3 = pack8(B3b.lo, B3b.hi);
      acc[0][0] = __builtin_amdgcn_mfma_f32_16x16x32_bf16(af0, bf0, acc[0][0], 0, 0, 0);
      acc[0][1] = __builtin_amdgcn_mfma_f32_16x16x32_bf16(af0, bf1, acc[0][1], 0, 0, 0);
      acc[0][2] = __builtin_amdgcn_mfma_f32_16x16x32_bf16(af0, bf2, acc[0][2], 0, 0, 0);
      acc[0][3] = __builtin_amdgcn_mfma_f32_16x16x32_bf16(af0, bf3, acc[0][3], 0, 0, 0);
      acc[1][0] = __builtin_amdgcn_mfma_f32_16x16x32_bf16(af1, bf0, acc[1][0], 0, 0, 0);
      acc[1][1] = __builtin_amdgcn_mfma_f32_16x16x32_bf16(af1, bf1, acc[1][1], 0, 0, 0);
      acc[1][2] = __builtin_amdgcn_mfma_f32_16x16x32_bf16(af1, bf2, acc[1][2], 0, 0, 0);
      acc[1][3] = __builtin_amdgcn_mfma_f32_16x16x32_bf16(af1, bf3, acc[1][3], 0, 0, 0);
    }
  }

  __syncthreads();                      // nls writes visible to all waves

  // ---- Phase B: distance/power straight from the C-fragment layout ----
  // C layout (verified): m = wm + i*16 + quad*4 + reg, n = j*16 + lrow.

  // pair mask applied ONCE by zeroing acc registers (distance loop unmasked)
  const int ligN = lig_counts[b];
  #pragma unroll
  for (int j = 0; j < 4; ++j) {
    const bool nv = (r0 + j * 16 + lrow) < recN;
    #pragma unroll
    for (int i = 0; i < 2; ++i)
      #pragma unroll
      for (int reg = 0; reg < 4; ++reg) {
        const bool mv = (wm + i * 16 + quad * 4 + reg) < ligN;
        if (!(nv && mv)) acc[i][j][reg] = 0.f;
      }
  }

  float rcx[4], rcy[4], rcz[4];
  #pragma unroll
  for (int j = 0; j < 4; ++j) {
    const float* rp = rec_coord + (size_t)(b * R_ + r0 + j * 16 + lrow) * 3;
    rcx[j] = rp[0]; rcy[j] = rp[1]; rcz[j] = rp[2];
  }

  if (e == 0)      phaseB<0>(acc, nls, rcx, rcy, rcz, wm, quad, lane, wave, smr);
  else if (e == 1) phaseB<1>(acc, nls, rcx, rcy, rcz, wm, quad, lane, wave, smr);
  else if (e == 2) phaseB<2>(acc, nls, rcx, rcy, rcz, wm, quad, lane, wave, smr);
  else if (e == 3) phaseB<3>(acc, nls, rcx, rcy, rcz, wm, quad, lane, wave, smr);
  else             phaseB<4>(acc, nls, rcx, rcy, rcz, wm, quad, lane, wave, smr);

  __syncthreads();
  if (tid < T_) {
    float s = smr[0][tid] + smr[1][tid] + smr[2][tid] + smr[3][tid];
    atomicAdd(&out[b * T_ + tid], s);
  }
}

// ---------------------------------------------------------------------------
extern "C" void kernel_launch(void* const* d_in, const int* in_sizes, int n_in,
                              void* d_out, int out_size, void* d_ws, size_t ws_size,
                              hipStream_t stream) {
  const float* lig_feat   = (const float*)d_in[0];
  const float* rec_feat   = (const float*)d_in[1];
  const float* lig_coord  = (const float*)d_in[2];
  const float* rec_coord  = (const float*)d_in[3];
  const float* pre_rot    = (const float*)d_in[4];
  const float* trans      = (const float*)d_in[5];
  const int*   lig_counts = (const int*)d_in[6];
  const int*   rec_counts = (const int*)d_in[7];
  float* out = (float*)d_out;

  // ws: new_lig [B,T,L,3] f32 (196KB) — only intermediate that remains
  float* new_lig = (float*)d_ws;

  prep_kernel<<<dim3(B_ * T_), dim3(L_), 0, stream>>>(lig_coord, pre_rot, trans,
                                                      new_lig, out);
  fused_kernel<<<dim3(R_ / 64, E_, B_), dim3(256), 0, stream>>>(
      lig_feat, rec_feat, rec_coord, lig_counts, rec_counts, new_lig, out);
}

// Round 5
// 164.995 us; speedup vs baseline: 1.2167x; 1.2167x over previous
//
#include <hip/hip_runtime.h>
#include <hip/hip_bf16.h>

// Problem constants (from reference): B,T,L,R,E,F
#define B_ 8
#define T_ 16
#define L_ 128
#define R_ 1024
#define E_ 5
#define F_ 512

typedef short short8 __attribute__((ext_vector_type(8)));
typedef float floatx4 __attribute__((ext_vector_type(4)));
typedef unsigned short ushort4v __attribute__((ext_vector_type(4)));

// fp32 -> bf16 bits, round-half-up
__device__ __forceinline__ unsigned short f2bf(float f) {
  unsigned u = __float_as_uint(f);
  return (unsigned short)((u + 0x8000u) >> 16);
}

__device__ __forceinline__ short8 pack8(floatx4 lo, floatx4 hi) {
  short8 v;
  v[0] = (short)f2bf(lo[0]); v[1] = (short)f2bf(lo[1]);
  v[2] = (short)f2bf(lo[2]); v[3] = (short)f2bf(lo[3]);
  v[4] = (short)f2bf(hi[0]); v[5] = (short)f2bf(hi[1]);
  v[6] = (short)f2bf(hi[2]); v[7] = (short)f2bf(hi[3]);
  return v;
}

// async 16B global->LDS DMA; lane i's data lands at ldsbase + i*16
__device__ __forceinline__ void stage16(const float* g, float* lds) {
  __builtin_amdgcn_global_load_lds(
      (const __attribute__((address_space(1))) void*)g,
      (__attribute__((address_space(3))) void*)lds, 16, 0, 0);
}

// s_waitcnt immediates (gfx9 encoding): lgkmcnt=15 (don't care), expcnt=7,
// vmcnt in bits [3:0] (hi bits [15:14] zero for vmcnt<16)
#define WAITCNT_VM6 0xF76   // vmcnt(6): prev chunk's 6 DMAs done, 6 newer in flight
#define WAITCNT_VM0 0xF70   // vmcnt(0)

// ---------------------------------------------------------------------------
// Kernel 1: rot = QR(pre_rot).Q (LAPACK Householder convention), then
// new_lig[b,t,l,:] = rot[b,t] @ lig_coord[b,l] + trans[b,t].
// Also zeroes out[bt] so the reduce kernel can atomicAdd.
// ---------------------------------------------------------------------------
__global__ void prep_kernel(const float* __restrict__ lig_coord,
                            const float* __restrict__ pre_rot,
                            const float* __restrict__ trans,
                            float* __restrict__ new_lig,
                            float* __restrict__ out) {
  int bt = blockIdx.x;
  __shared__ float Qs[3][3];
  if (threadIdx.x == 0) {
    out[bt] = 0.f;                      // zero output for atomic accumulation
    float a[3][3], q[3][3];
    #pragma unroll
    for (int i = 0; i < 3; ++i)
      #pragma unroll
      for (int j = 0; j < 3; ++j) {
        a[i][j] = pre_rot[(bt * 3 + i) * 3 + j];
        q[i][j] = (i == j) ? 1.f : 0.f;
      }
    for (int k = 0; k < 3; ++k) {
      float alpha = a[k][k];
      float xn2 = 0.f;
      for (int i = k + 1; i < 3; ++i) xn2 += a[i][k] * a[i][k];
      float nrm = sqrtf(alpha * alpha + xn2);
      if (xn2 > 0.f && nrm > 0.f) {
        float beta = (alpha >= 0.f) ? -nrm : nrm;
        float tau = (beta - alpha) / beta;
        float inv = 1.f / (alpha - beta);
        float v[3] = {0.f, 0.f, 0.f};
        v[k] = 1.f;
        for (int i = k + 1; i < 3; ++i) v[i] = a[i][k] * inv;
        for (int j = k; j < 3; ++j) {
          float w = 0.f;
          for (int i = k; i < 3; ++i) w += v[i] * a[i][j];
          w *= tau;
          for (int i = k; i < 3; ++i) a[i][j] -= w * v[i];
        }
        for (int i = 0; i < 3; ++i) {
          float w = 0.f;
          for (int j = k; j < 3; ++j) w += q[i][j] * v[j];
          w *= tau;
          for (int j = k; j < 3; ++j) q[i][j] -= w * v[j];
        }
      }
    }
    for (int i = 0; i < 3; ++i)
      for (int j = 0; j < 3; ++j) Qs[i][j] = q[i][j];
  }
  __syncthreads();
  int b = bt >> 4;
  int l = threadIdx.x;
  float cx = lig_coord[(b * L_ + l) * 3 + 0];
  float cy = lig_coord[(b * L_ + l) * 3 + 1];
  float cz = lig_coord[(b * L_ + l) * 3 + 2];
  float nx = Qs[0][0] * cx + Qs[0][1] * cy + Qs[0][2] * cz + trans[bt * 3 + 0];
  float ny = Qs[1][0] * cx + Qs[1][1] * cy + Qs[1][2] * cz + trans[bt * 3 + 1];
  float nz = Qs[2][0] * cx + Qs[2][1] * cy + Qs[2][2] * cz + trans[bt * 3 + 2];
  float* o = new_lig + ((size_t)bt * L_ + l) * 3;
  o[0] = nx; o[1] = ny; o[2] = nz;
}

// ---------------------------------------------------------------------------
// Kernel 2: atn[b,e,l,r] (bf16) = sum_f lig_feat[b,l,e,f] * rec_feat[b,r,e,f]
// Proven round-0 mainloop: raw s_barrier + manual s_waitcnt vmcnt(6) — wait
// only for the CURRENT chunk's 6 DMAs, keep the next chunk's 6 in flight
// across the barrier.
//   iter k: [barrier: readers of buf[cur^1] retired] -> stage(k+1 -> cur^1)
//           -> vmcnt(6) (stage(k) landed) -> barrier -> ds_read/MFMA buf[cur]
// Output stored bf16 (halves WRITE + reduce's read; ~0.2% extra rounding).
// Tile: M=128 x N=64 per block (640 blocks); wave = 32M x 64N; BK=32, dbuf.
// ---------------------------------------------------------------------------
__launch_bounds__(256)
__global__ void gemm_kernel(const float* __restrict__ lig_feat,
                            const float* __restrict__ rec_feat,
                            const int* __restrict__ rec_counts,
                            unsigned short* __restrict__ atn) {
  const int rt = blockIdx.x;    // 0..15
  const int e  = blockIdx.y;    // 0..4
  const int b  = blockIdx.z;    // 0..7
  const int r0 = rt * 64;
  if (r0 >= rec_counts[b]) return;   // tile fully masked downstream (uniform)

  __shared__ float As[2][128 * 32];  // [buf][row][32k], 16B chunks swizzled
  __shared__ float Bs[2][64 * 32];

  const int tid  = threadIdx.x;
  const int wave = tid >> 6;
  const int lane = tid & 63;
  const int lrow = lane & 15;
  const int quad = lane >> 4;
  const int wm   = wave * 32;

  // staging: wave stages 8 rows/instr; 16B-chunk swizzled on the GLOBAL
  // side (chunk ^= row&7) since the DMA's LDS dst is linear base+lane*16.
  const int lr8 = lane >> 3;
  const int sw  = (lane & 7) ^ lr8;
  const float* ga[4];
  #pragma unroll
  for (int i = 0; i < 4; ++i) {
    int row = wave * 32 + i * 8 + lr8;
    ga[i] = lig_feat + ((size_t)(b * L_ + row) * E_ + e) * F_ + sw * 4;
  }
  const float* gb[2];
  #pragma unroll
  for (int i = 0; i < 2; ++i) {
    int row = wave * 16 + i * 8 + lr8;
    gb[i] = rec_feat + ((size_t)(b * R_ + r0 + row) * E_ + e) * F_ + sw * 4;
  }

  floatx4 acc[2][4];
  #pragma unroll
  for (int i = 0; i < 2; ++i)
    #pragma unroll
    for (int j = 0; j < 4; ++j)
      acc[i][j] = (floatx4){0.f, 0.f, 0.f, 0.f};

  // fragment-read physical chunks (row&7 == lane&7 for all fragment rows)
  const int c0 = (2 * quad) ^ (lane & 7);

  // stage chunk 0 -> buf 0 (6 DMA loads per wave)
  #pragma unroll
  for (int i = 0; i < 4; ++i) stage16(ga[i], &As[0][(wave * 32 + i * 8) * 32]);
  #pragma unroll
  for (int i = 0; i < 2; ++i) stage16(gb[i], &Bs[0][(wave * 16 + i * 8) * 32]);

  #pragma unroll 1
  for (int kc = 0; kc < 16; ++kc) {
    const int cur = kc & 1;
    if (kc > 0)
      __builtin_amdgcn_s_barrier();     // all waves done reading buf[cur^1]
    if (kc < 15) {                      // prefetch next chunk -> buf[cur^1]
      const int col = (kc + 1) * 32;
      #pragma unroll
      for (int i = 0; i < 4; ++i)
        stage16(ga[i] + col, &As[cur ^ 1][(wave * 32 + i * 8) * 32]);
      #pragma unroll
      for (int i = 0; i < 2; ++i)
        stage16(gb[i] + col, &Bs[cur ^ 1][(wave * 16 + i * 8) * 32]);
      __builtin_amdgcn_s_waitcnt(WAITCNT_VM6);  // stage(kc) done; 6 in flight
    } else {
      __builtin_amdgcn_s_waitcnt(WAITCNT_VM0);
    }
    __builtin_amdgcn_s_barrier();       // every wave's stage(kc) landed
    __builtin_amdgcn_sched_barrier(0);  // keep ds_reads below the barrier

    short8 af[2], bfv[4];
    #pragma unroll
    for (int i = 0; i < 2; ++i) {
      const float* base = &As[cur][(wm + i * 16 + lrow) * 32];
      af[i] = pack8(*(const floatx4*)(base + c0 * 4),
                    *(const floatx4*)(base + (c0 ^ 1) * 4));
    }
    #pragma unroll
    for (int j = 0; j < 4; ++j) {
      const float* base = &Bs[cur][(j * 16 + lrow) * 32];
      bfv[j] = pack8(*(const floatx4*)(base + c0 * 4),
                     *(const floatx4*)(base + (c0 ^ 1) * 4));
    }
    #pragma unroll
    for (int i = 0; i < 2; ++i)
      #pragma unroll
      for (int j = 0; j < 4; ++j)
        acc[i][j] = __builtin_amdgcn_mfma_f32_16x16x32_bf16(af[i], bfv[j], acc[i][j], 0, 0, 0);
  }

  // store C tile bf16: atn[((b*E+e)*L + m)*R + r0 + n]
  const size_t base = (size_t)(b * E_ + e) * L_ * R_;
  #pragma unroll
  for (int i = 0; i < 2; ++i)
    #pragma unroll
    for (int j = 0; j < 4; ++j)
      #pragma unroll
      for (int reg = 0; reg < 4; ++reg) {
        int m = wm + i * 16 + quad * 4 + reg;
        int n = j * 16 + lrow;
        atn[base + (size_t)m * R_ + r0 + n] = f2bf(acc[i][j][reg]);
      }
}

// ---------------------------------------------------------------------------
// Kernel 3: U[b,t] += sum_{l,r,e} atn[b,e,l,r] * d(b,t,l,r)^exp[e]
// One block per (b,l). Thread owns r=4*tid..+4: 5x8B bf16 atn loads +
// 3 float4 coord loads all issue up front, ~960 FLOP amortizes.
// Wave-uniform skip of fully-masked 256-r spans. Per-(b,l) U[16] is
// atomicAdd'ed straight into out (zeroed by prep) — no partial round-trip,
// no final kernel.
// ---------------------------------------------------------------------------
__launch_bounds__(256)
__global__ void reduce_kernel(const unsigned short* __restrict__ atn,
                              const float* __restrict__ new_lig,
                              const float* __restrict__ rec_coord,
                              const int* __restrict__ lig_counts,
                              const int* __restrict__ rec_counts,
                              float* __restrict__ out) {
  const int b = blockIdx.x >> 7;
  const int l = blockIdx.x & 127;
  const int tid = threadIdx.x;
  if (l >= lig_counts[b]) return;       // out already zeroed; contributes 0
  const int recN = rec_counts[b];
  const int wave = tid >> 6;

  __shared__ float nl[T_][3];
  __shared__ float sm[4][T_];
  if (tid < T_ * 3)
    nl[tid / 3][tid % 3] =
        new_lig[((size_t)(b * T_ + tid / 3) * L_ + l) * 3 + (tid % 3)];
  __syncthreads();

  float u[T_];
  #pragma unroll
  for (int t = 0; t < T_; ++t) u[t] = 0.f;

  if (wave * 256 < recN) {              // wave-uniform skip of masked span
    const int r = tid * 4;
    const size_t plane = (size_t)L_ * R_;
    const unsigned short* atnB = atn + (size_t)b * E_ * plane + (size_t)l * R_ + r;
    const float* rcB = rec_coord + ((size_t)b * R_ + r) * 3;

    ushort4v a4[5];
    #pragma unroll
    for (int e = 0; e < 5; ++e) a4[e] = *(const ushort4v*)(atnB + e * plane);
    floatx4 q0 = *(const floatx4*)(rcB + 0);
    floatx4 q1 = *(const floatx4*)(rcB + 4);
    floatx4 q2 = *(const floatx4*)(rcB + 8);
    float px[4] = {q0[0], q0[3], q1[2], q2[1]};
    float py[4] = {q0[1], q1[0], q1[3], q2[2]};
    float pz[4] = {q0[2], q1[1], q2[0], q2[3]};
    float am[5][4];
    #pragma unroll
    for (int e = 0; e < 5; ++e)
      #pragma unroll
      for (int s = 0; s < 4; ++s)
        am[e][s] = (r + s < recN)
                       ? __uint_as_float((unsigned)a4[e][s] << 16)
                       : 0.f;

    #pragma unroll
    for (int t = 0; t < T_; ++t) {
      float acc = 0.f;
      #pragma unroll
      for (int s = 0; s < 4; ++s) {
        float dx = nl[t][0] - px[s];
        float dy = nl[t][1] - py[s];
        float dz = nl[t][2] - pz[s];
        float d2 = fmaf(dx, dx, fmaf(dy, dy, dz * dz));
        d2 = fmaxf(d2, 1e-20f);
        float rs  = rsqrtf(d2);
        float rs2 = rs * rs;
        float rs3 = rs2 * rs;
        float d1  = d2 * rs;
        float c = am[0][s] * rs3;
        c = fmaf(am[1][s], rs2, c);
        c = fmaf(am[2][s], rs, c);
        c = fmaf(am[3][s], d1, c);
        c = fmaf(am[4][s], d2, c);
        acc += c;
      }
      u[t] += acc;
    }
  }

  #pragma unroll
  for (int t = 0; t < T_; ++t) {
    float v = u[t];
    #pragma unroll
    for (int m = 32; m > 0; m >>= 1) v += __shfl_xor(v, m, 64);
    if ((tid & 63) == 0) sm[wave][t] = v;
  }
  __syncthreads();
  if (tid < T_)
    atomicAdd(&out[b * T_ + tid],
              sm[0][tid] + sm[1][tid] + sm[2][tid] + sm[3][tid]);
}

// ---------------------------------------------------------------------------
extern "C" void kernel_launch(void* const* d_in, const int* in_sizes, int n_in,
                              void* d_out, int out_size, void* d_ws, size_t ws_size,
                              hipStream_t stream) {
  const float* lig_feat   = (const float*)d_in[0];
  const float* rec_feat   = (const float*)d_in[1];
  const float* lig_coord  = (const float*)d_in[2];
  const float* rec_coord  = (const float*)d_in[3];
  const float* pre_rot    = (const float*)d_in[4];
  const float* trans      = (const float*)d_in[5];
  const int*   lig_counts = (const int*)d_in[6];
  const int*   rec_counts = (const int*)d_in[7];
  float* out = (float*)d_out;

  // ws: new_lig [B,T,L,3] f32 (192KB) | atn [B,E,L,R] bf16 (10.5MB)
  float* new_lig = (float*)d_ws;
  unsigned short* atn = (unsigned short*)(new_lig + (size_t)B_ * T_ * L_ * 3);

  prep_kernel<<<dim3(B_ * T_), dim3(L_), 0, stream>>>(lig_coord, pre_rot, trans,
                                                      new_lig, out);
  gemm_kernel<<<dim3(R_ / 64, E_, B_), dim3(256), 0, stream>>>(lig_feat, rec_feat,
                                                               rec_counts, atn);
  reduce_kernel<<<dim3(B_ * L_), dim3(256), 0, stream>>>(atn, new_lig, rec_coord,
                                                         lig_counts, rec_counts, out);
}